// Round 3
// baseline (780.583 us; speedup 1.0000x reference)
//
#include <hip/hip_runtime.h>
#include <hip/hip_bf16.h>

// GCN 3-layer forward on MI355X — round 3.
//  * Atomic-free CSR build: 2-level bucket sort (dst>>8 buckets, LDS histograms,
//    matrix scan, LDS-cursor scatter, per-bucket exact CSR). No global atomics.
//  * All 3 dense transforms fused into the gather/aggregation kernels
//    (shfl-broadcast vec x matT with 4 rows/wave; weights pre-transposed,
//    read from global, L1/L2 resident). No standalone GEMMs.
// Math identical to round 2 (all f32): absmax should stay ~1.2e-4.

#define TPB 256
#define NB1 64  // level-1 blocks (hist/scatter); chunk = ceil(E/NB1)

// ---------------- weight transpose: wT[k*O + n] = W[n*K + k] ----------------
__global__ void k_transpose(const float* __restrict__ W, int O, int K, float* __restrict__ wT) {
  int idx = blockIdx.x * blockDim.x + threadIdx.x;
  if (idx < O * K) {
    int n = idx / K, k = idx % K;
    wT[k * O + n] = W[idx];
  }
}

// ---------------- CSR build (atomic-free, 2-level) ----------------

// level-1 histogram: gh[bin*NB1 + blk] = count of edges in blk's chunk with dst>>8 == bin
__global__ __launch_bounds__(256) void k_hist(const int* __restrict__ dst, int E, int C,
                                              int NBUK, int* __restrict__ gh) {
  __shared__ int h[512];
  int t = threadIdx.x, b = blockIdx.x;
  for (int i = t; i < NBUK; i += 256) h[i] = 0;
  __syncthreads();
  int beg = b * C, end = min(beg + C, E);
  for (int i = beg + t; i < end; i += 256) atomicAdd(&h[dst[i] >> 8], 1);
  __syncthreads();
  for (int i = t; i < NBUK; i += 256) gh[i * NB1 + b] = h[i];
}

// generic 3-kernel exclusive scan over int array of length L
__global__ __launch_bounds__(256) void k_sum256(const int* __restrict__ g, int L,
                                                int* __restrict__ part) {
  __shared__ int red[256];
  int t = threadIdx.x;
  int idx = blockIdx.x * 256 + t;
  red[t] = (idx < L) ? g[idx] : 0;
  __syncthreads();
  for (int off = 128; off > 0; off >>= 1) {
    if (t < off) red[t] += red[t + off];
    __syncthreads();
  }
  if (t == 0) part[blockIdx.x] = red[0];
}

__global__ __launch_bounds__(128) void k_scan_part(int* __restrict__ part, int NP) {
  __shared__ int sh[128];
  int t = threadIdx.x;
  int v = (t < NP) ? part[t] : 0;
  sh[t] = v;
  __syncthreads();
  for (int off = 1; off < 128; off <<= 1) {
    int u = (t >= off) ? sh[t - off] : 0;
    __syncthreads();
    sh[t] += u;
    __syncthreads();
  }
  if (t < NP) part[t] = sh[t] - v;  // exclusive
}

__global__ __launch_bounds__(256) void k_scan_apply(const int* __restrict__ g, int L,
                                                    const int* __restrict__ part,
                                                    int* __restrict__ gout) {
  __shared__ int sh[256];
  int t = threadIdx.x;
  int idx = blockIdx.x * 256 + t;
  int v = (idx < L) ? g[idx] : 0;
  sh[t] = v;
  __syncthreads();
  for (int off = 1; off < 256; off <<= 1) {
    int u = (t >= off) ? sh[t - off] : 0;
    __syncthreads();
    sh[t] += u;
    __syncthreads();
  }
  if (idx < L) gout[idx] = part[blockIdx.x] + sh[t] - v;
}

// level-1 scatter into bucket-sorted edge buffer (LDS cursors only)
__global__ __launch_bounds__(256) void k_scatter(const int* __restrict__ src,
                                                 const int* __restrict__ dst, int E, int C,
                                                 int NBUK, const int* __restrict__ gscan,
                                                 int* __restrict__ es, int* __restrict__ ed) {
  __shared__ int cur[512];
  int t = threadIdx.x, b = blockIdx.x;
  for (int i = t; i < NBUK; i += 256) cur[i] = gscan[i * NB1 + b];
  __syncthreads();
  int beg = b * C, end = min(beg + C, E);
  for (int i = beg + t; i < end; i += 256) {
    int d = dst[i];
    int p = atomicAdd(&cur[d >> 8], 1);
    es[p] = src[i];
    ed[p] = d;
  }
}

// level-2: one block per bucket (256 nodes) -> exact CSR + dinv
__global__ __launch_bounds__(256) void k_csr(const int* __restrict__ es, const int* __restrict__ ed,
                                             const int* __restrict__ gscan, int NBUK, int N, int E,
                                             int* __restrict__ rowptr, float* __restrict__ dinv,
                                             int* __restrict__ col) {
  __shared__ int cnt[256];
  __shared__ int scn[256];
  __shared__ int cur[256];
  int b = blockIdx.x, t = threadIdx.x;
  int ebeg = gscan[b * NB1];
  int eend = (b + 1 < NBUK) ? gscan[(b + 1) * NB1] : E;
  cnt[t] = 0;
  __syncthreads();
  for (int i = ebeg + t; i < eend; i += 256) atomicAdd(&cnt[ed[i] & 255], 1);
  __syncthreads();
  int c = cnt[t];
  scn[t] = c;
  __syncthreads();
  for (int off = 1; off < 256; off <<= 1) {
    int v = (t >= off) ? scn[t - off] : 0;
    __syncthreads();
    scn[t] += v;
    __syncthreads();
  }
  int excl = scn[t] - c;
  int node = b * 256 + t;
  if (node < N) {
    rowptr[node] = ebeg + excl;
    dinv[node] = rsqrtf((float)(c + 1));  // +1 self-loop
  }
  cur[t] = ebeg + excl;
  __syncthreads();
  for (int i = ebeg + t; i < eend; i += 256) {
    int p = atomicAdd(&cur[ed[i] & 255], 1);
    col[p] = es[i];
  }
  if (b == 0 && t == 0) rowptr[N] = E;
}

// ---------------- fused layer kernels ----------------
// wave handles 4 consecutive rows; lane = feature.

// K1: h1[r][0:128] = relu( (agg x)[r][0:64] @ W1^T + b1 )
__global__ __launch_bounds__(256) void k_layer1(const float* __restrict__ x,
                                                const float* __restrict__ dinv,
                                                const int* __restrict__ rowptr,
                                                const int* __restrict__ col,
                                                const float* __restrict__ wT1,  // [64][128]
                                                const float* __restrict__ b1,
                                                float* __restrict__ h1, int N) {
  int wave = threadIdx.x >> 6, lane = threadIdx.x & 63;
  int rbase = (blockIdx.x * 4 + wave) * 4;
  float a[4];
#pragma unroll
  for (int q = 0; q < 4; ++q) {
    int r = rbase + q;
    float acc = 0.f;
    if (r < N) {
      float di = dinv[r];
      acc = di * x[(size_t)r * 64 + lane];
      int r0 = rowptr[r], r1 = rowptr[r + 1];
      for (int base = r0; base < r1; base += 64) {
        int m = min(64, r1 - base);
        int ce = (base + lane < r1) ? col[base + lane] : 0;
        for (int j = 0; j < m; ++j) {
          int s2 = __shfl(ce, j);
          acc += dinv[s2] * x[(size_t)s2 * 64 + lane];
        }
      }
      acc *= di;
    }
    a[q] = acc;
  }
  // transform: u[n] = sum_k a[k] * wT1[k][n], n in {2lane, 2lane+1}
  float u0[4] = {0.f, 0.f, 0.f, 0.f}, u1[4] = {0.f, 0.f, 0.f, 0.f};
  for (int k = 0; k < 64; ++k) {
    float2 w = *(const float2*)&wT1[k * 128 + 2 * lane];
#pragma unroll
    for (int q = 0; q < 4; ++q) {
      float ak = __shfl(a[q], k);
      u0[q] += ak * w.x;
      u1[q] += ak * w.y;
    }
  }
  float2 bb = *(const float2*)&b1[2 * lane];
#pragma unroll
  for (int q = 0; q < 4; ++q) {
    int r = rbase + q;
    if (r < N) {
      float2 o;
      o.x = fmaxf(u0[q] + bb.x, 0.f);
      o.y = fmaxf(u1[q] + bb.y, 0.f);
      *(float2*)&h1[(size_t)r * 128 + 2 * lane] = o;
    }
  }
}

// K2: z[r][0:64] = relu( (agg h1)[r][0:128] @ W2^T + b2 ) @ W3^T
__global__ __launch_bounds__(256) void k_layer2(const float* __restrict__ h1,
                                                const float* __restrict__ dinv,
                                                const int* __restrict__ rowptr,
                                                const int* __restrict__ col,
                                                const float* __restrict__ wT2,  // [128][128]
                                                const float* __restrict__ b2,
                                                const float* __restrict__ wT3,  // [128][64]
                                                float* __restrict__ z, int N) {
  int wave = threadIdx.x >> 6, lane = threadIdx.x & 63;
  int rbase = (blockIdx.x * 4 + wave) * 4;
  float a0[4], a1[4];
#pragma unroll
  for (int q = 0; q < 4; ++q) {
    int r = rbase + q;
    float x0 = 0.f, x1 = 0.f;
    if (r < N) {
      float di = dinv[r];
      const float* hr = &h1[(size_t)r * 128];
      x0 = di * hr[lane];
      x1 = di * hr[64 + lane];
      int r0 = rowptr[r], r1 = rowptr[r + 1];
      for (int base = r0; base < r1; base += 64) {
        int m = min(64, r1 - base);
        int ce = (base + lane < r1) ? col[base + lane] : 0;
        for (int j = 0; j < m; ++j) {
          int s2 = __shfl(ce, j);
          float ds = dinv[s2];
          const float* hs = &h1[(size_t)s2 * 128];
          x0 += ds * hs[lane];
          x1 += ds * hs[64 + lane];
        }
      }
      x0 *= di;
      x1 *= di;
    }
    a0[q] = x0;
    a1[q] = x1;
  }
  // u[n] = sum_k a[k] * wT2[k][n], n in {2lane, 2lane+1}
  float u0[4] = {0.f, 0.f, 0.f, 0.f}, u1[4] = {0.f, 0.f, 0.f, 0.f};
  for (int k = 0; k < 64; ++k) {
    float2 w = *(const float2*)&wT2[k * 128 + 2 * lane];
#pragma unroll
    for (int q = 0; q < 4; ++q) {
      float ak = __shfl(a0[q], k);
      u0[q] += ak * w.x;
      u1[q] += ak * w.y;
    }
  }
  for (int k = 0; k < 64; ++k) {
    float2 w = *(const float2*)&wT2[(64 + k) * 128 + 2 * lane];
#pragma unroll
    for (int q = 0; q < 4; ++q) {
      float ak = __shfl(a1[q], k);
      u0[q] += ak * w.x;
      u1[q] += ak * w.y;
    }
  }
  float2 bb = *(const float2*)&b2[2 * lane];
#pragma unroll
  for (int q = 0; q < 4; ++q) {
    u0[q] = fmaxf(u0[q] + bb.x, 0.f);
    u1[q] = fmaxf(u1[q] + bb.y, 0.f);
  }
  // z[m] = sum_n u[n] * wT3[n][m], m = lane; u[2*n2] in u0 lane n2, u[2*n2+1] in u1 lane n2
  float zz[4] = {0.f, 0.f, 0.f, 0.f};
  for (int n2 = 0; n2 < 64; ++n2) {
    float w3a = wT3[(2 * n2) * 64 + lane];
    float w3b = wT3[(2 * n2 + 1) * 64 + lane];
#pragma unroll
    for (int q = 0; q < 4; ++q) {
      zz[q] += __shfl(u0[q], n2) * w3a + __shfl(u1[q], n2) * w3b;
    }
  }
#pragma unroll
  for (int q = 0; q < 4; ++q) {
    int r = rbase + q;
    if (r < N) z[(size_t)r * 64 + lane] = zz[q];
  }
}

// K3: out[r] = softmax( (agg z)[r] + b3 )
__global__ __launch_bounds__(256) void k_layer3(const float* __restrict__ zin,
                                                const float* __restrict__ dinv,
                                                const int* __restrict__ rowptr,
                                                const int* __restrict__ col,
                                                const float* __restrict__ b3,
                                                float* __restrict__ out, int N) {
  int wid = blockIdx.x * 4 + (threadIdx.x >> 6);
  int lane = threadIdx.x & 63;
  if (wid >= N) return;
  float di = dinv[wid];
  float acc = di * zin[(size_t)wid * 64 + lane];
  int r0 = rowptr[wid], r1 = rowptr[wid + 1];
  for (int base = r0; base < r1; base += 64) {
    int m = min(64, r1 - base);
    int ce = (base + lane < r1) ? col[base + lane] : 0;
    for (int j = 0; j < m; ++j) {
      int s2 = __shfl(ce, j);
      acc += dinv[s2] * zin[(size_t)s2 * 64 + lane];
    }
  }
  float v = di * acc + b3[lane];
  float mx = v;
#pragma unroll
  for (int o = 32; o > 0; o >>= 1) mx = fmaxf(mx, __shfl_xor(mx, o));
  float p = expf(v - mx);
  float sum = p;
#pragma unroll
  for (int o = 32; o > 0; o >>= 1) sum += __shfl_xor(sum, o);
  out[(size_t)wid * 64 + lane] = p / sum;
}

// ---------------- launch ----------------

extern "C" void kernel_launch(void* const* d_in, const int* in_sizes, int n_in,
                              void* d_out, int out_size, void* d_ws, size_t ws_size,
                              hipStream_t stream) {
  const float* x  = (const float*)d_in[0];
  const int*   ei = (const int*)d_in[1];
  const float* W1 = (const float*)d_in[2];
  const float* b1 = (const float*)d_in[3];
  const float* W2 = (const float*)d_in[4];
  const float* b2 = (const float*)d_in[5];
  const float* W3 = (const float*)d_in[6];
  const float* b3 = (const float*)d_in[7];
  float* out = (float*)d_out;

  const int N = in_sizes[0] / 64;
  const int E = in_sizes[1] / 2;
  const int* esrc = ei;
  const int* edst = ei + E;

  const int NBUK = (N + 255) / 256;          // level-1 buckets (dst>>8)
  const int C1 = (E + NB1 - 1) / NB1;        // edges per level-1 block
  const int L = NBUK * NB1;                  // gh matrix size
  const int NA = (L + 255) / 256;            // scan blocks

  char* w = (char*)d_ws;
  auto take = [&](size_t bytes) -> void* {
    void* p = (void*)w;
    w += (bytes + 255) & ~(size_t)255;
    return p;
  };
  int*   rowptr = (int*)take((size_t)(N + 1) * 4);
  float* dinv   = (float*)take((size_t)N * 4);
  int*   col    = (int*)take((size_t)E * 4);
  int*   gh     = (int*)take((size_t)L * 4);
  int*   gscan  = (int*)take((size_t)L * 4);
  int*   part   = (int*)take((size_t)NA * 4);
  int*   es     = (int*)take((size_t)E * 4);
  int*   ed     = (int*)take((size_t)E * 4);
  float* wT1    = (float*)take((size_t)64 * 128 * 4);
  float* wT2    = (float*)take((size_t)128 * 128 * 4);
  float* wT3    = (float*)take((size_t)128 * 64 * 4);
  float* h1     = (float*)take((size_t)N * 128 * 4);
  float* zbuf   = (float*)take((size_t)N * 64 * 4);

  // weight transposes (tiny)
  k_transpose<<<(128 * 64 + 255) / 256, 256, 0, stream>>>(W1, 128, 64, wT1);
  k_transpose<<<(128 * 128 + 255) / 256, 256, 0, stream>>>(W2, 128, 128, wT2);
  k_transpose<<<(64 * 128 + 255) / 256, 256, 0, stream>>>(W3, 64, 128, wT3);

  // CSR build (no global atomics)
  k_hist<<<NB1, 256, 0, stream>>>(edst, E, C1, NBUK, gh);
  k_sum256<<<NA, 256, 0, stream>>>(gh, L, part);
  k_scan_part<<<1, 128, 0, stream>>>(part, NA);
  k_scan_apply<<<NA, 256, 0, stream>>>(gh, L, part, gscan);
  k_scatter<<<NB1, 256, 0, stream>>>(esrc, edst, E, C1, NBUK, gscan, es, ed);
  k_csr<<<NBUK, 256, 0, stream>>>(es, ed, gscan, NBUK, N, E, rowptr, dinv, col);

  const int fblocks = (N + 15) / 16;  // 16 rows/block (4 waves x 4 rows)
  k_layer1<<<fblocks, 256, 0, stream>>>(x, dinv, rowptr, col, wT1, b1, h1, N);
  k_layer2<<<fblocks, 256, 0, stream>>>(h1, dinv, rowptr, col, wT2, b2, wT3, zbuf, N);
  k_layer3<<<(N + 3) / 4, 256, 0, stream>>>(zbuf, dinv, rowptr, col, b3, out, N);
}

// Round 4
// 520.729 us; speedup vs baseline: 1.4990x; 1.4990x over previous
//
#include <hip/hip_runtime.h>
#include <hip/hip_bf16.h>

// GCN 3-layer forward on MI355X — round 4.
//  * De-fused layers (round-3 fusion cost 4x wave parallelism on a latency-bound
//    gather). 1 row per wave in aggregators.
//  * Aggregators use vec4 edge-groups: 4 (64f) / 2 (128f) edges in flight per
//    wave, float4 per lane, butterfly cross-group reduce.
//  * dinv folded into stored features (prescale x; GEMM epilogues emit dinv*h),
//    so the gather inner loop is a pure float4 sum.
//  * Atomic-free CSR build (bucket sort by dst>>8), int2 edge payload.
// All f32 math; absmax ~1.2e-4 expected (threshold 3.9e-4).

#define NB1 256  // level-1 blocks for hist/scatter

// ---------------- CSR build (atomic-free, 2-level) ----------------

__global__ __launch_bounds__(256) void k_hist(const int* __restrict__ dst, int E, int C,
                                              int NBUK, int* __restrict__ gh) {
  __shared__ int h[512];
  int t = threadIdx.x, b = blockIdx.x;
  for (int i = t; i < NBUK; i += 256) h[i] = 0;
  __syncthreads();
  int beg = b * C, end = min(beg + C, E);
  for (int i = beg + t; i < end; i += 256) atomicAdd(&h[dst[i] >> 8], 1);
  __syncthreads();
  for (int i = t; i < NBUK; i += 256) gh[i * NB1 + b] = h[i];
}

__global__ __launch_bounds__(256) void k_sum256(const int* __restrict__ g, int L,
                                                int* __restrict__ part) {
  __shared__ int red[256];
  int t = threadIdx.x;
  int idx = blockIdx.x * 256 + t;
  red[t] = (idx < L) ? g[idx] : 0;
  __syncthreads();
  for (int off = 128; off > 0; off >>= 1) {
    if (t < off) red[t] += red[t + off];
    __syncthreads();
  }
  if (t == 0) part[blockIdx.x] = red[0];
}

__global__ __launch_bounds__(512) void k_scan_part(int* __restrict__ part, int NP) {
  __shared__ int sh[512];
  int t = threadIdx.x;
  int v = (t < NP) ? part[t] : 0;
  sh[t] = v;
  __syncthreads();
  for (int off = 1; off < 512; off <<= 1) {
    int u = (t >= off) ? sh[t - off] : 0;
    __syncthreads();
    sh[t] += u;
    __syncthreads();
  }
  if (t < NP) part[t] = sh[t] - v;  // exclusive
}

__global__ __launch_bounds__(256) void k_scan_apply(const int* __restrict__ g, int L,
                                                    const int* __restrict__ part,
                                                    int* __restrict__ gout) {
  __shared__ int sh[256];
  int t = threadIdx.x;
  int idx = blockIdx.x * 256 + t;
  int v = (idx < L) ? g[idx] : 0;
  sh[t] = v;
  __syncthreads();
  for (int off = 1; off < 256; off <<= 1) {
    int u = (t >= off) ? sh[t - off] : 0;
    __syncthreads();
    sh[t] += u;
    __syncthreads();
  }
  if (idx < L) gout[idx] = part[blockIdx.x] + sh[t] - v;
}

__global__ __launch_bounds__(256) void k_scatter(const int* __restrict__ src,
                                                 const int* __restrict__ dst, int E, int C,
                                                 int NBUK, const int* __restrict__ gscan,
                                                 int2* __restrict__ epak) {
  __shared__ int cur[512];
  int t = threadIdx.x, b = blockIdx.x;
  for (int i = t; i < NBUK; i += 256) cur[i] = gscan[i * NB1 + b];
  __syncthreads();
  int beg = b * C, end = min(beg + C, E);
  for (int i = beg + t; i < end; i += 256) {
    int d = dst[i];
    int p = atomicAdd(&cur[d >> 8], 1);
    epak[p] = make_int2(src[i], d);
  }
}

__global__ __launch_bounds__(256) void k_csr(const int2* __restrict__ epak,
                                             const int* __restrict__ gscan, int NBUK, int N, int E,
                                             int* __restrict__ rowptr, float* __restrict__ dinv,
                                             int* __restrict__ col) {
  __shared__ int cnt[256];
  __shared__ int scn[256];
  __shared__ int cur[256];
  int b = blockIdx.x, t = threadIdx.x;
  int ebeg = gscan[b * NB1];
  int eend = (b + 1 < NBUK) ? gscan[(b + 1) * NB1] : E;
  cnt[t] = 0;
  __syncthreads();
  for (int i = ebeg + t; i < eend; i += 256) atomicAdd(&cnt[epak[i].y & 255], 1);
  __syncthreads();
  int c = cnt[t];
  scn[t] = c;
  __syncthreads();
  for (int off = 1; off < 256; off <<= 1) {
    int v = (t >= off) ? scn[t - off] : 0;
    __syncthreads();
    scn[t] += v;
    __syncthreads();
  }
  int excl = scn[t] - c;
  int node = b * 256 + t;
  if (node < N) {
    rowptr[node] = ebeg + excl;
    dinv[node] = rsqrtf((float)(c + 1));  // +1 self-loop
  }
  cur[t] = ebeg + excl;
  __syncthreads();
  for (int i = ebeg + t; i < eend; i += 256) {
    int2 e = epak[i];
    int p = atomicAdd(&cur[e.y & 255], 1);
    col[p] = e.x;
  }
  if (b == 0 && t == 0) rowptr[N] = E;
}

// ---------------- prescale: xp = dinv[row] * x ----------------
__global__ __launch_bounds__(256) void k_prescale(const float* __restrict__ x,
                                                  const float* __restrict__ dinv,
                                                  float* __restrict__ xp, int N) {
  int i = blockIdx.x * 256 + threadIdx.x;  // one float4 per thread
  if (i < N * 16) {
    int row = i >> 4;
    float4 v = ((const float4*)x)[i];
    float d = dinv[row];
    v.x *= d; v.y *= d; v.z *= d; v.w *= d;
    ((float4*)xp)[i] = v;
  }
}

// ---------------- aggregation (pull, 1 row/wave, vec4 edge-groups) ----------------
// input hp is pre-scaled by dinv; output = dinv[r] * (sum_nbrs hp[s] + hp[r]).

// F=64: 4 edge-groups x 16 lanes x float4. EPI: 0 plain, 1 +bias then softmax.
template <int EPI>
__global__ __launch_bounds__(256) void k_agg64(const float* __restrict__ hp,
                                               const float* __restrict__ dinv,
                                               const int* __restrict__ rowptr,
                                               const int* __restrict__ col,
                                               const float* __restrict__ bias,
                                               float* __restrict__ out, int N) {
  int wid = blockIdx.x * 4 + (threadIdx.x >> 6);
  int lane = threadIdx.x & 63;
  if (wid >= N) return;
  int g = lane >> 4;
  int fl = (lane & 15) * 4;
  float4 acc = make_float4(0.f, 0.f, 0.f, 0.f);
  int r0 = rowptr[wid], r1 = rowptr[wid + 1];
  for (int base = r0; base < r1; base += 64) {
    int mm = min(64, r1 - base);
    int ce = (base + lane < r1) ? col[base + lane] : 0;
    for (int j = 0; j < mm; j += 4) {
      int idx = j + g;
      int s2 = __shfl(ce, idx);
      if (idx < mm) {
        const float4 v = *(const float4*)&hp[(size_t)s2 * 64 + fl];
        acc.x += v.x; acc.y += v.y; acc.z += v.z; acc.w += v.w;
      }
    }
  }
#pragma unroll
  for (int o = 16; o < 64; o <<= 1) {
    acc.x += __shfl_xor(acc.x, o);
    acc.y += __shfl_xor(acc.y, o);
    acc.z += __shfl_xor(acc.z, o);
    acc.w += __shfl_xor(acc.w, o);
  }
  const float4 self = *(const float4*)&hp[(size_t)wid * 64 + fl];
  float di = dinv[wid];
  float4 v;
  v.x = di * (acc.x + self.x);
  v.y = di * (acc.y + self.y);
  v.z = di * (acc.z + self.z);
  v.w = di * (acc.w + self.w);
  if (EPI == 1) {
    const float4 b4 = *(const float4*)&bias[fl];
    v.x += b4.x; v.y += b4.y; v.z += b4.z; v.w += b4.w;
    float mx = fmaxf(fmaxf(v.x, v.y), fmaxf(v.z, v.w));
#pragma unroll
    for (int o = 1; o < 16; o <<= 1) mx = fmaxf(mx, __shfl_xor(mx, o));
    v.x = expf(v.x - mx);
    v.y = expf(v.y - mx);
    v.z = expf(v.z - mx);
    v.w = expf(v.w - mx);
    float sum = v.x + v.y + v.z + v.w;
#pragma unroll
    for (int o = 1; o < 16; o <<= 1) sum += __shfl_xor(sum, o);
    float inv = 1.0f / sum;
    v.x *= inv; v.y *= inv; v.z *= inv; v.w *= inv;
  }
  if (lane < 16) *(float4*)&out[(size_t)wid * 64 + fl] = v;
}

// F=128: 2 edge-groups x 32 lanes x float4.
__global__ __launch_bounds__(256) void k_agg128(const float* __restrict__ hp,
                                                const float* __restrict__ dinv,
                                                const int* __restrict__ rowptr,
                                                const int* __restrict__ col,
                                                float* __restrict__ out, int N) {
  int wid = blockIdx.x * 4 + (threadIdx.x >> 6);
  int lane = threadIdx.x & 63;
  if (wid >= N) return;
  int g = lane >> 5;
  int fl = (lane & 31) * 4;
  float4 acc = make_float4(0.f, 0.f, 0.f, 0.f);
  int r0 = rowptr[wid], r1 = rowptr[wid + 1];
  for (int base = r0; base < r1; base += 64) {
    int mm = min(64, r1 - base);
    int ce = (base + lane < r1) ? col[base + lane] : 0;
    for (int j = 0; j < mm; j += 2) {
      int idx = j + g;
      int s2 = __shfl(ce, idx);
      if (idx < mm) {
        const float4 v = *(const float4*)&hp[(size_t)s2 * 128 + fl];
        acc.x += v.x; acc.y += v.y; acc.z += v.z; acc.w += v.w;
      }
    }
  }
  acc.x += __shfl_xor(acc.x, 32);
  acc.y += __shfl_xor(acc.y, 32);
  acc.z += __shfl_xor(acc.z, 32);
  acc.w += __shfl_xor(acc.w, 32);
  const float4 self = *(const float4*)&hp[(size_t)wid * 128 + fl];
  float di = dinv[wid];
  float4 v;
  v.x = di * (acc.x + self.x);
  v.y = di * (acc.y + self.y);
  v.z = di * (acc.z + self.z);
  v.w = di * (acc.w + self.w);
  if (lane < 32) *(float4*)&out[(size_t)wid * 128 + fl] = v;
}

// ---------------- dense GEMM: out = [relu](in @ W^T + b) [* dinv[row]] ----------------

template <int K, int NOUT, bool RELU, bool BIAS, bool PRESCALE>
__global__ __launch_bounds__(256) void k_gemm(const float* __restrict__ in,
                                              const float* __restrict__ W,
                                              const float* __restrict__ bias,
                                              const float* __restrict__ dinv,
                                              float* __restrict__ out, int M) {
  constexpr int KC = 64;
  constexpr int R = 64;
  constexpr int TN = 4;
  constexpr int NG = NOUT / TN;   // 32 or 16
  constexpr int RG = 256 / NG;    // 8 or 16
  constexpr int TM = R / RG;      // 8 or 4

  __shared__ float wT[KC][NOUT + 4];
  __shared__ float inT[KC][R + 4];

  int t = threadIdx.x;
  int ng = t % NG, rg = t / NG;
  int n0 = ng * TN, r0 = rg * TM;
  int rowbase = blockIdx.x * R;

  float acc[TM][TN];
#pragma unroll
  for (int i = 0; i < TM; ++i)
#pragma unroll
    for (int j = 0; j < TN; ++j) acc[i][j] = 0.0f;

  for (int kc = 0; kc < K; kc += KC) {
    constexpr int WF4 = NOUT * KC / 4;
    for (int m = t; m < WF4; m += 256) {
      int kk4 = m % (KC / 4);
      int n = m / (KC / 4);
      const float4 w4 = *(const float4*)&W[(size_t)n * K + kc + kk4 * 4];
      wT[kk4 * 4 + 0][n] = w4.x;
      wT[kk4 * 4 + 1][n] = w4.y;
      wT[kk4 * 4 + 2][n] = w4.z;
      wT[kk4 * 4 + 3][n] = w4.w;
    }
    constexpr int IF4 = R * KC / 4;
    for (int m = t; m < IF4; m += 256) {
      int kk4 = m % (KC / 4);
      int r = m / (KC / 4);
      int row = rowbase + r;
      float4 v4 = make_float4(0.f, 0.f, 0.f, 0.f);
      if (row < M) v4 = *(const float4*)&in[(size_t)row * K + kc + kk4 * 4];
      inT[kk4 * 4 + 0][r] = v4.x;
      inT[kk4 * 4 + 1][r] = v4.y;
      inT[kk4 * 4 + 2][r] = v4.z;
      inT[kk4 * 4 + 3][r] = v4.w;
    }
    __syncthreads();

#pragma unroll 8
    for (int k = 0; k < KC; ++k) {
      float4 w4 = *(const float4*)&wT[k][n0];
      float4 iv4[TM / 4];
#pragma unroll
      for (int i4 = 0; i4 < TM / 4; ++i4) iv4[i4] = *(const float4*)&inT[k][r0 + i4 * 4];
      const float* iv = (const float*)iv4;
#pragma unroll
      for (int i = 0; i < TM; ++i) {
        acc[i][0] += iv[i] * w4.x;
        acc[i][1] += iv[i] * w4.y;
        acc[i][2] += iv[i] * w4.z;
        acc[i][3] += iv[i] * w4.w;
      }
    }
    __syncthreads();
  }

  float4 b4 = make_float4(0.f, 0.f, 0.f, 0.f);
  if (BIAS) b4 = *(const float4*)&bias[n0];
#pragma unroll
  for (int i = 0; i < TM; ++i) {
    int row = rowbase + r0 + i;
    if (row < M) {
      float4 o;
      o.x = acc[i][0] + b4.x;
      o.y = acc[i][1] + b4.y;
      o.z = acc[i][2] + b4.z;
      o.w = acc[i][3] + b4.w;
      if (RELU) {
        o.x = fmaxf(o.x, 0.f);
        o.y = fmaxf(o.y, 0.f);
        o.z = fmaxf(o.z, 0.f);
        o.w = fmaxf(o.w, 0.f);
      }
      if (PRESCALE) {
        float d = dinv[row];
        o.x *= d; o.y *= d; o.z *= d; o.w *= d;
      }
      *(float4*)&out[(size_t)row * NOUT + n0] = o;
    }
  }
}

// ---------------- launch ----------------

extern "C" void kernel_launch(void* const* d_in, const int* in_sizes, int n_in,
                              void* d_out, int out_size, void* d_ws, size_t ws_size,
                              hipStream_t stream) {
  const float* x  = (const float*)d_in[0];
  const int*   ei = (const int*)d_in[1];
  const float* W1 = (const float*)d_in[2];
  const float* b1 = (const float*)d_in[3];
  const float* W2 = (const float*)d_in[4];
  const float* b2 = (const float*)d_in[5];
  const float* W3 = (const float*)d_in[6];
  const float* b3 = (const float*)d_in[7];
  float* out = (float*)d_out;

  const int N = in_sizes[0] / 64;
  const int E = in_sizes[1] / 2;
  const int* esrc = ei;
  const int* edst = ei + E;

  const int NBUK = (N + 255) / 256;      // buckets (dst>>8), 391
  const int C1 = (E + NB1 - 1) / NB1;    // edges per level-1 block
  const int L = NBUK * NB1;
  const int NA = (L + 255) / 256;        // <= 512

  char* w = (char*)d_ws;
  auto take = [&](size_t bytes) -> void* {
    void* p = (void*)w;
    w += (bytes + 255) & ~(size_t)255;
    return p;
  };
  int*   rowptr = (int*)take((size_t)(N + 1) * 4);
  float* dinv   = (float*)take((size_t)N * 4);
  int*   col    = (int*)take((size_t)E * 4);
  int*   gh     = (int*)take((size_t)L * 4);
  int*   gscan  = (int*)take((size_t)L * 4);
  int*   part   = (int*)take((size_t)NA * 4);
  int2*  epak   = (int2*)take((size_t)E * 8);
  float* bufA   = (float*)take((size_t)N * 128 * 4);
  float* bufB   = (float*)take((size_t)N * 128 * 4);

  // CSR build (no global atomics)
  k_hist<<<NB1, 256, 0, stream>>>(edst, E, C1, NBUK, gh);
  k_sum256<<<NA, 256, 0, stream>>>(gh, L, part);
  k_scan_part<<<1, 512, 0, stream>>>(part, NA);
  k_scan_apply<<<NA, 256, 0, stream>>>(gh, L, part, gscan);
  k_scatter<<<NB1, 256, 0, stream>>>(esrc, edst, E, C1, NBUK, gscan, epak);
  k_csr<<<NBUK, 256, 0, stream>>>(epak, gscan, NBUK, N, E, rowptr, dinv, col);

  const int aggblocks = (N + 3) / 4;
  const int gemmblocks = (N + 63) / 64;

  // xp = dinv*x
  k_prescale<<<(N * 16 + 255) / 256, 256, 0, stream>>>(x, dinv, bufA, N);
  // A1 = agg(xp)   (true aggregated x)
  k_agg64<0><<<aggblocks, 256, 0, stream>>>(bufA, dinv, rowptr, col, nullptr, bufB, N);
  // h1p = dinv * relu(A1 @ W1^T + b1)
  k_gemm<64, 128, true, true, true><<<gemmblocks, 256, 0, stream>>>(bufB, W1, b1, dinv, bufA, N);
  // A2 = agg(h1p)
  k_agg128<<<aggblocks, 256, 0, stream>>>(bufA, dinv, rowptr, col, bufB, N);
  // u = relu(A2 @ W2^T + b2)
  k_gemm<128, 128, true, true, false><<<gemmblocks, 256, 0, stream>>>(bufB, W2, b2, dinv, bufA, N);
  // zp = dinv * (u @ W3^T)
  k_gemm<128, 64, false, false, true><<<gemmblocks, 256, 0, stream>>>(bufA, W3, nullptr, dinv, bufB, N);
  // out = softmax(agg(zp) + b3)
  k_agg64<1><<<aggblocks, 256, 0, stream>>>(bufB, dinv, rowptr, col, b3, out, N);
}

// Round 5
// 431.086 us; speedup vs baseline: 1.8107x; 1.2079x over previous
//
#include <hip/hip_runtime.h>
#include <hip/hip_bf16.h>

// GCN 3-layer forward on MI355X — round 5.
//  * fp16 storage for all gathered feature tables (x·dinv, h1·dinv, z·dinv):
//    halves gather traffic (layer2 row 512B -> 256B) and doubles edges in
//    flight per wave. Accumulation stays f32; softmax attenuates the ~1e-4
//    logit noise, absmax stays well under threshold.
//  * 8 (64f) / 4 (128f) edge-groups x 16B per lane, inner loop unrolled 2x.
//  * Bucket-sort edge payload packed to one int (src | (dst&255)<<24).
//  * GEMM2 runs in-place (blocks own disjoint 64-row tiles).

#define NB1 256  // level-1 blocks for hist/scatter

typedef __attribute__((ext_vector_type(4))) _Float16 half4;
typedef __attribute__((ext_vector_type(8))) _Float16 half8;

// ---------------- CSR build (atomic-free, 2-level) ----------------

__global__ __launch_bounds__(256) void k_hist(const int* __restrict__ dst, int E, int C,
                                              int NBUK, int* __restrict__ gh) {
  __shared__ int h[512];
  int t = threadIdx.x, b = blockIdx.x;
  for (int i = t; i < NBUK; i += 256) h[i] = 0;
  __syncthreads();
  int beg = b * C, end = min(beg + C, E);
  for (int i = beg + t; i < end; i += 256) atomicAdd(&h[dst[i] >> 8], 1);
  __syncthreads();
  for (int i = t; i < NBUK; i += 256) gh[i * NB1 + b] = h[i];
}

__global__ __launch_bounds__(256) void k_sum256(const int* __restrict__ g, int L,
                                                int* __restrict__ part) {
  __shared__ int red[256];
  int t = threadIdx.x;
  int idx = blockIdx.x * 256 + t;
  red[t] = (idx < L) ? g[idx] : 0;
  __syncthreads();
  for (int off = 128; off > 0; off >>= 1) {
    if (t < off) red[t] += red[t + off];
    __syncthreads();
  }
  if (t == 0) part[blockIdx.x] = red[0];
}

__global__ __launch_bounds__(512) void k_scan_part(int* __restrict__ part, int NP) {
  __shared__ int sh[512];
  int t = threadIdx.x;
  int v = (t < NP) ? part[t] : 0;
  sh[t] = v;
  __syncthreads();
  for (int off = 1; off < 512; off <<= 1) {
    int u = (t >= off) ? sh[t - off] : 0;
    __syncthreads();
    sh[t] += u;
    __syncthreads();
  }
  if (t < NP) part[t] = sh[t] - v;  // exclusive
}

__global__ __launch_bounds__(256) void k_scan_apply(const int* __restrict__ g, int L,
                                                    const int* __restrict__ part,
                                                    int* __restrict__ gout) {
  __shared__ int sh[256];
  int t = threadIdx.x;
  int idx = blockIdx.x * 256 + t;
  int v = (idx < L) ? g[idx] : 0;
  sh[t] = v;
  __syncthreads();
  for (int off = 1; off < 256; off <<= 1) {
    int u = (t >= off) ? sh[t - off] : 0;
    __syncthreads();
    sh[t] += u;
    __syncthreads();
  }
  if (idx < L) gout[idx] = part[blockIdx.x] + sh[t] - v;
}

// payload: src | (dst&255)<<24  (src < 2^17)
__global__ __launch_bounds__(256) void k_scatter(const int* __restrict__ src,
                                                 const int* __restrict__ dst, int E, int C,
                                                 int NBUK, const int* __restrict__ gscan,
                                                 int* __restrict__ epak) {
  __shared__ int cur[512];
  int t = threadIdx.x, b = blockIdx.x;
  for (int i = t; i < NBUK; i += 256) cur[i] = gscan[i * NB1 + b];
  __syncthreads();
  int beg = b * C, end = min(beg + C, E);
  for (int i = beg + t; i < end; i += 256) {
    int d = dst[i];
    int p = atomicAdd(&cur[d >> 8], 1);
    epak[p] = src[i] | ((d & 255) << 24);
  }
}

__global__ __launch_bounds__(256) void k_csr(const int* __restrict__ epak,
                                             const int* __restrict__ gscan, int NBUK, int N, int E,
                                             int* __restrict__ rowptr, float* __restrict__ dinv,
                                             int* __restrict__ col) {
  __shared__ int cnt[256];
  __shared__ int scn[256];
  __shared__ int cur[256];
  int b = blockIdx.x, t = threadIdx.x;
  int ebeg = gscan[b * NB1];
  int eend = (b + 1 < NBUK) ? gscan[(b + 1) * NB1] : E;
  cnt[t] = 0;
  __syncthreads();
  for (int i = ebeg + t; i < eend; i += 256) atomicAdd(&cnt[(epak[i] >> 24) & 255], 1);
  __syncthreads();
  int c = cnt[t];
  scn[t] = c;
  __syncthreads();
  for (int off = 1; off < 256; off <<= 1) {
    int v = (t >= off) ? scn[t - off] : 0;
    __syncthreads();
    scn[t] += v;
    __syncthreads();
  }
  int excl = scn[t] - c;
  int node = b * 256 + t;
  if (node < N) {
    rowptr[node] = ebeg + excl;
    dinv[node] = rsqrtf((float)(c + 1));  // +1 self-loop
  }
  cur[t] = ebeg + excl;
  __syncthreads();
  for (int i = ebeg + t; i < eend; i += 256) {
    int e = epak[i];
    int p = atomicAdd(&cur[(e >> 24) & 255], 1);
    col[p] = e & 0xFFFFFF;
  }
  if (b == 0 && t == 0) rowptr[N] = E;
}

// ---------------- prescale: xp = (half)(dinv[row] * x) ----------------
__global__ __launch_bounds__(256) void k_prescaleh(const float* __restrict__ x,
                                                   const float* __restrict__ dinv,
                                                   _Float16* __restrict__ xp, int N) {
  int i = blockIdx.x * 256 + threadIdx.x;  // one float4 per thread
  if (i < N * 16) {
    int row = i >> 4;
    float4 v = ((const float4*)x)[i];
    float d = dinv[row];
    half4 o;
    o[0] = (_Float16)(v.x * d);
    o[1] = (_Float16)(v.y * d);
    o[2] = (_Float16)(v.z * d);
    o[3] = (_Float16)(v.w * d);
    ((half4*)xp)[i] = o;
  }
}

// ---------------- aggregation (pull, 1 row/wave, fp16 tables) ----------------
// input hp pre-scaled by dinv; output = dinv[r] * (sum_nbrs hp[s] + hp[r]) [f32].

// F=64: 8 edge-groups x 8 lanes x 8 halves (16B). EPI: 0 plain, 1 +bias softmax.
template <int EPI>
__global__ __launch_bounds__(256) void k_agg64h(const _Float16* __restrict__ hp,
                                                const float* __restrict__ dinv,
                                                const int* __restrict__ rowptr,
                                                const int* __restrict__ col,
                                                const float* __restrict__ bias,
                                                float* __restrict__ out, int N) {
  int wid = blockIdx.x * 4 + (threadIdx.x >> 6);
  int lane = threadIdx.x & 63;
  if (wid >= N) return;
  int g = lane >> 3;
  int fl = (lane & 7) * 8;
  float acc[8] = {0.f, 0.f, 0.f, 0.f, 0.f, 0.f, 0.f, 0.f};
  int r0 = rowptr[wid], r1 = rowptr[wid + 1];
  for (int base = r0; base < r1; base += 64) {
    int mm = min(64, r1 - base);
    int ce = (base + lane < r1) ? col[base + lane] : 0;
    for (int j = 0; j < mm; j += 16) {
      int i0 = j + g, i1 = j + 8 + g;
      int s0 = __shfl(ce, i0);
      int s1 = __shfl(ce, i1);
      if (i0 < mm) {
        half8 v = *(const half8*)&hp[(size_t)s0 * 64 + fl];
#pragma unroll
        for (int k = 0; k < 8; ++k) acc[k] += (float)v[k];
      }
      if (i1 < mm) {
        half8 v = *(const half8*)&hp[(size_t)s1 * 64 + fl];
#pragma unroll
        for (int k = 0; k < 8; ++k) acc[k] += (float)v[k];
      }
    }
  }
#pragma unroll
  for (int o = 8; o < 64; o <<= 1) {
#pragma unroll
    for (int k = 0; k < 8; ++k) acc[k] += __shfl_xor(acc[k], o);
  }
  half8 sv = *(const half8*)&hp[(size_t)wid * 64 + fl];
  float di = dinv[wid];
  float v[8];
#pragma unroll
  for (int k = 0; k < 8; ++k) v[k] = di * (acc[k] + (float)sv[k]);
  if (EPI == 1) {
    float4 ba = *(const float4*)&bias[fl];
    float4 bb = *(const float4*)&bias[fl + 4];
    v[0] += ba.x; v[1] += ba.y; v[2] += ba.z; v[3] += ba.w;
    v[4] += bb.x; v[5] += bb.y; v[6] += bb.z; v[7] += bb.w;
    float mx = v[0];
#pragma unroll
    for (int k = 1; k < 8; ++k) mx = fmaxf(mx, v[k]);
#pragma unroll
    for (int o = 1; o < 8; o <<= 1) mx = fmaxf(mx, __shfl_xor(mx, o));
    float s = 0.f;
#pragma unroll
    for (int k = 0; k < 8; ++k) {
      v[k] = expf(v[k] - mx);
      s += v[k];
    }
#pragma unroll
    for (int o = 1; o < 8; o <<= 1) s += __shfl_xor(s, o);
    float inv = 1.0f / s;
#pragma unroll
    for (int k = 0; k < 8; ++k) v[k] *= inv;
  }
  if (lane < 8) {
    float4 o0 = make_float4(v[0], v[1], v[2], v[3]);
    float4 o1 = make_float4(v[4], v[5], v[6], v[7]);
    *(float4*)&out[(size_t)wid * 64 + fl] = o0;
    *(float4*)&out[(size_t)wid * 64 + fl + 4] = o1;
  }
}

// F=128: 4 edge-groups x 16 lanes x 8 halves (16B).
__global__ __launch_bounds__(256) void k_agg128h(const _Float16* __restrict__ hp,
                                                 const float* __restrict__ dinv,
                                                 const int* __restrict__ rowptr,
                                                 const int* __restrict__ col,
                                                 float* __restrict__ out, int N) {
  int wid = blockIdx.x * 4 + (threadIdx.x >> 6);
  int lane = threadIdx.x & 63;
  if (wid >= N) return;
  int g = lane >> 4;
  int fl = (lane & 15) * 8;
  float acc[8] = {0.f, 0.f, 0.f, 0.f, 0.f, 0.f, 0.f, 0.f};
  int r0 = rowptr[wid], r1 = rowptr[wid + 1];
  for (int base = r0; base < r1; base += 64) {
    int mm = min(64, r1 - base);
    int ce = (base + lane < r1) ? col[base + lane] : 0;
    for (int j = 0; j < mm; j += 8) {
      int i0 = j + g, i1 = j + 4 + g;
      int s0 = __shfl(ce, i0);
      int s1 = __shfl(ce, i1);
      if (i0 < mm) {
        half8 v = *(const half8*)&hp[(size_t)s0 * 128 + fl];
#pragma unroll
        for (int k = 0; k < 8; ++k) acc[k] += (float)v[k];
      }
      if (i1 < mm) {
        half8 v = *(const half8*)&hp[(size_t)s1 * 128 + fl];
#pragma unroll
        for (int k = 0; k < 8; ++k) acc[k] += (float)v[k];
      }
    }
  }
#pragma unroll
  for (int o = 16; o < 64; o <<= 1) {
#pragma unroll
    for (int k = 0; k < 8; ++k) acc[k] += __shfl_xor(acc[k], o);
  }
  half8 sv = *(const half8*)&hp[(size_t)wid * 128 + fl];
  float di = dinv[wid];
  float v[8];
#pragma unroll
  for (int k = 0; k < 8; ++k) v[k] = di * (acc[k] + (float)sv[k]);
  if (lane < 16) {
    float4 o0 = make_float4(v[0], v[1], v[2], v[3]);
    float4 o1 = make_float4(v[4], v[5], v[6], v[7]);
    *(float4*)&out[(size_t)wid * 128 + fl] = o0;
    *(float4*)&out[(size_t)wid * 128 + fl + 4] = o1;
  }
}

// ---------------- dense GEMM: out = [relu](in @ W^T + b) [* dinv[row]] ----------------
// OUTF16: write _Float16, else f32. In-place (out==in) is safe per-block.

template <int K, int NOUT, bool RELU, bool BIAS, bool PRESCALE, bool OUTF16>
__global__ __launch_bounds__(256) void k_gemm(const float* __restrict__ in,
                                              const float* __restrict__ W,
                                              const float* __restrict__ bias,
                                              const float* __restrict__ dinv,
                                              void* __restrict__ outp, int M) {
  constexpr int KC = 64;
  constexpr int R = 64;
  constexpr int TN = 4;
  constexpr int NG = NOUT / TN;
  constexpr int RG = 256 / NG;
  constexpr int TM = R / RG;

  __shared__ float wT[KC][NOUT + 4];
  __shared__ float inT[KC][R + 4];

  int t = threadIdx.x;
  int ng = t % NG, rg = t / NG;
  int n0 = ng * TN, r0 = rg * TM;
  int rowbase = blockIdx.x * R;

  float acc[TM][TN];
#pragma unroll
  for (int i = 0; i < TM; ++i)
#pragma unroll
    for (int j = 0; j < TN; ++j) acc[i][j] = 0.0f;

  for (int kc = 0; kc < K; kc += KC) {
    constexpr int WF4 = NOUT * KC / 4;
    for (int m = t; m < WF4; m += 256) {
      int kk4 = m % (KC / 4);
      int n = m / (KC / 4);
      const float4 w4 = *(const float4*)&W[(size_t)n * K + kc + kk4 * 4];
      wT[kk4 * 4 + 0][n] = w4.x;
      wT[kk4 * 4 + 1][n] = w4.y;
      wT[kk4 * 4 + 2][n] = w4.z;
      wT[kk4 * 4 + 3][n] = w4.w;
    }
    constexpr int IF4 = R * KC / 4;
    for (int m = t; m < IF4; m += 256) {
      int kk4 = m % (KC / 4);
      int r = m / (KC / 4);
      int row = rowbase + r;
      float4 v4 = make_float4(0.f, 0.f, 0.f, 0.f);
      if (row < M) v4 = *(const float4*)&in[(size_t)row * K + kc + kk4 * 4];
      inT[kk4 * 4 + 0][r] = v4.x;
      inT[kk4 * 4 + 1][r] = v4.y;
      inT[kk4 * 4 + 2][r] = v4.z;
      inT[kk4 * 4 + 3][r] = v4.w;
    }
    __syncthreads();

#pragma unroll 8
    for (int k = 0; k < KC; ++k) {
      float4 w4 = *(const float4*)&wT[k][n0];
      float4 iv4[TM / 4];
#pragma unroll
      for (int i4 = 0; i4 < TM / 4; ++i4) iv4[i4] = *(const float4*)&inT[k][r0 + i4 * 4];
      const float* iv = (const float*)iv4;
#pragma unroll
      for (int i = 0; i < TM; ++i) {
        acc[i][0] += iv[i] * w4.x;
        acc[i][1] += iv[i] * w4.y;
        acc[i][2] += iv[i] * w4.z;
        acc[i][3] += iv[i] * w4.w;
      }
    }
    __syncthreads();
  }

  float4 b4 = make_float4(0.f, 0.f, 0.f, 0.f);
  if (BIAS) b4 = *(const float4*)&bias[n0];
#pragma unroll
  for (int i = 0; i < TM; ++i) {
    int row = rowbase + r0 + i;
    if (row < M) {
      float4 o;
      o.x = acc[i][0] + b4.x;
      o.y = acc[i][1] + b4.y;
      o.z = acc[i][2] + b4.z;
      o.w = acc[i][3] + b4.w;
      if (RELU) {
        o.x = fmaxf(o.x, 0.f);
        o.y = fmaxf(o.y, 0.f);
        o.z = fmaxf(o.z, 0.f);
        o.w = fmaxf(o.w, 0.f);
      }
      if (PRESCALE) {
        float d = dinv[row];
        o.x *= d; o.y *= d; o.z *= d; o.w *= d;
      }
      if (OUTF16) {
        half4 h;
        h[0] = (_Float16)o.x;
        h[1] = (_Float16)o.y;
        h[2] = (_Float16)o.z;
        h[3] = (_Float16)o.w;
        *(half4*)&((_Float16*)outp)[(size_t)row * NOUT + n0] = h;
      } else {
        *(float4*)&((float*)outp)[(size_t)row * NOUT + n0] = o;
      }
    }
  }
}

// ---------------- launch ----------------

extern "C" void kernel_launch(void* const* d_in, const int* in_sizes, int n_in,
                              void* d_out, int out_size, void* d_ws, size_t ws_size,
                              hipStream_t stream) {
  const float* x  = (const float*)d_in[0];
  const int*   ei = (const int*)d_in[1];
  const float* W1 = (const float*)d_in[2];
  const float* b1 = (const float*)d_in[3];
  const float* W2 = (const float*)d_in[4];
  const float* b2 = (const float*)d_in[5];
  const float* W3 = (const float*)d_in[6];
  const float* b3 = (const float*)d_in[7];
  float* out = (float*)d_out;

  const int N = in_sizes[0] / 64;
  const int E = in_sizes[1] / 2;
  const int* esrc = ei;
  const int* edst = ei + E;

  const int NBUK = (N + 255) / 256;
  const int C1 = (E + NB1 - 1) / NB1;
  const int L = NBUK * NB1;
  const int NA = (L + 255) / 256;

  char* w = (char*)d_ws;
  auto take = [&](size_t bytes) -> void* {
    void* p = (void*)w;
    w += (bytes + 255) & ~(size_t)255;
    return p;
  };
  // persistent CSR data
  int*   rowptr = (int*)take((size_t)(N + 1) * 4);
  float* dinv   = (float*)take((size_t)N * 4);
  int*   col    = (int*)take((size_t)E * 4);
  int*   gh     = (int*)take((size_t)L * 4);
  int*   gscan  = (int*)take((size_t)L * 4);
  int*   part   = (int*)take((size_t)NA * 4);
  // feature buffers (lifetimes disjoint where aliased)
  _Float16* hx  = (_Float16*)take((size_t)N * 64 * 2);   // prescaled x; later reused as z (hz)
  float* bufA   = (float*)take((size_t)N * 64 * 4);      // A1 (f32, 64f)
  _Float16* h1  = (_Float16*)take((size_t)N * 128 * 2);  // h1p (half)
  float* bufB   = (float*)take((size_t)N * 128 * 4);     // A2 / u (f32, 128f)
  // epak aliases bufB: dead before bufB's first write (both after k_csr)
  int*   epak   = (int*)bufB;
  _Float16* hz  = hx;  // x-table dead after layer-1 agg

  // CSR build (no global atomics)
  k_hist<<<NB1, 256, 0, stream>>>(edst, E, C1, NBUK, gh);
  k_sum256<<<NA, 256, 0, stream>>>(gh, L, part);
  k_scan_part<<<1, 512, 0, stream>>>(part, NA);
  k_scan_apply<<<NA, 256, 0, stream>>>(gh, L, part, gscan);
  k_scatter<<<NB1, 256, 0, stream>>>(esrc, edst, E, C1, NBUK, gscan, epak);
  k_csr<<<NBUK, 256, 0, stream>>>(epak, gscan, NBUK, N, E, rowptr, dinv, col);

  const int aggblocks = (N + 3) / 4;
  const int gemmblocks = (N + 63) / 64;

  // xp = (half) dinv*x
  k_prescaleh<<<(N * 16 + 255) / 256, 256, 0, stream>>>(x, dinv, hx, N);
  // A1 = agg(xp)                                      [f32 N x 64]
  k_agg64h<0><<<aggblocks, 256, 0, stream>>>(hx, dinv, rowptr, col, nullptr, bufA, N);
  // h1p = (half) dinv * relu(A1 @ W1^T + b1)          [half N x 128]
  k_gemm<64, 128, true, true, true, true><<<gemmblocks, 256, 0, stream>>>(bufA, W1, b1, dinv, h1, N);
  // A2 = agg(h1p)                                     [f32 N x 128]
  k_agg128h<<<aggblocks, 256, 0, stream>>>(h1, dinv, rowptr, col, bufB, N);
  // u = relu(A2 @ W2^T + b2)  (in-place)              [f32 N x 128]
  k_gemm<128, 128, true, true, false, false><<<gemmblocks, 256, 0, stream>>>(bufB, W2, b2, dinv, bufB, N);
  // zp = (half) dinv * (u @ W3^T)                     [half N x 64]
  k_gemm<128, 64, false, false, true, true><<<gemmblocks, 256, 0, stream>>>(bufB, W3, nullptr, dinv, hz, N);
  // out = softmax(agg(zp) + b3)
  k_agg64h<1><<<aggblocks, 256, 0, stream>>>(hz, dinv, rowptr, col, b3, out, N);
}

// Round 7
// 357.608 us; speedup vs baseline: 2.1828x; 1.2055x over previous
//
#include <hip/hip_runtime.h>
#include <hip/hip_bf16.h>

// GCN 3-layer forward on MI355X — round 6 (resubmit; round-6 bench hit a
// GPU-acquisition timeout, no signal obtained).
//  * Dense transforms moved to MFMA (mfma_f32_16x16x32_f16, f32 accumulate):
//    k_mfma1 (64->128, bias+relu+dinv fused) and k_mfma23 (128->128->64 with
//    layer-2/3 fusion through a per-wave LDS scratch). Swapped operands so each
//    lane owns 4 consecutive output cols of one row -> half4 stores.
//  * Aggregators write fp16 tables directly (A1h, A2h); weights pre-converted
//    to fp16 by k_prep_w. f32 VALU GEMMs deleted.
//  * CSR build unchanged (atomic-free 2-level bucket sort).

#define NB1 256  // level-1 blocks for hist/scatter

typedef __attribute__((ext_vector_type(4))) _Float16 half4;
typedef __attribute__((ext_vector_type(8))) _Float16 half8;
typedef __attribute__((ext_vector_type(4))) float f32x4;

// ---------------- CSR build (atomic-free, 2-level) ----------------

__global__ __launch_bounds__(256) void k_hist(const int* __restrict__ dst, int E, int C,
                                              int NBUK, int* __restrict__ gh) {
  __shared__ int h[512];
  int t = threadIdx.x, b = blockIdx.x;
  for (int i = t; i < NBUK; i += 256) h[i] = 0;
  __syncthreads();
  int beg = b * C, end = min(beg + C, E);
  for (int i = beg + t; i < end; i += 256) atomicAdd(&h[dst[i] >> 8], 1);
  __syncthreads();
  for (int i = t; i < NBUK; i += 256) gh[i * NB1 + b] = h[i];
}

__global__ __launch_bounds__(256) void k_sum256(const int* __restrict__ g, int L,
                                                int* __restrict__ part) {
  __shared__ int red[256];
  int t = threadIdx.x;
  int idx = blockIdx.x * 256 + t;
  red[t] = (idx < L) ? g[idx] : 0;
  __syncthreads();
  for (int off = 128; off > 0; off >>= 1) {
    if (t < off) red[t] += red[t + off];
    __syncthreads();
  }
  if (t == 0) part[blockIdx.x] = red[0];
}

__global__ __launch_bounds__(512) void k_scan_part(int* __restrict__ part, int NP) {
  __shared__ int sh[512];
  int t = threadIdx.x;
  int v = (t < NP) ? part[t] : 0;
  sh[t] = v;
  __syncthreads();
  for (int off = 1; off < 512; off <<= 1) {
    int u = (t >= off) ? sh[t - off] : 0;
    __syncthreads();
    sh[t] += u;
    __syncthreads();
  }
  if (t < NP) part[t] = sh[t] - v;  // exclusive
}

__global__ __launch_bounds__(256) void k_scan_apply(const int* __restrict__ g, int L,
                                                    const int* __restrict__ part,
                                                    int* __restrict__ gout) {
  __shared__ int sh[256];
  int t = threadIdx.x;
  int idx = blockIdx.x * 256 + t;
  int v = (idx < L) ? g[idx] : 0;
  sh[t] = v;
  __syncthreads();
  for (int off = 1; off < 256; off <<= 1) {
    int u = (t >= off) ? sh[t - off] : 0;
    __syncthreads();
    sh[t] += u;
    __syncthreads();
  }
  if (idx < L) gout[idx] = part[blockIdx.x] + sh[t] - v;
}

// payload: src | (dst&255)<<24  (src < 2^17)
__global__ __launch_bounds__(256) void k_scatter(const int* __restrict__ src,
                                                 const int* __restrict__ dst, int E, int C,
                                                 int NBUK, const int* __restrict__ gscan,
                                                 int* __restrict__ epak) {
  __shared__ int cur[512];
  int t = threadIdx.x, b = blockIdx.x;
  for (int i = t; i < NBUK; i += 256) cur[i] = gscan[i * NB1 + b];
  __syncthreads();
  int beg = b * C, end = min(beg + C, E);
  for (int i = beg + t; i < end; i += 256) {
    int d = dst[i];
    int p = atomicAdd(&cur[d >> 8], 1);
    epak[p] = src[i] | ((d & 255) << 24);
  }
}

__global__ __launch_bounds__(256) void k_csr(const int* __restrict__ epak,
                                             const int* __restrict__ gscan, int NBUK, int N, int E,
                                             int* __restrict__ rowptr, float* __restrict__ dinv,
                                             int* __restrict__ col) {
  __shared__ int cnt[256];
  __shared__ int scn[256];
  __shared__ int cur[256];
  int b = blockIdx.x, t = threadIdx.x;
  int ebeg = gscan[b * NB1];
  int eend = (b + 1 < NBUK) ? gscan[(b + 1) * NB1] : E;
  cnt[t] = 0;
  __syncthreads();
  for (int i = ebeg + t; i < eend; i += 256) atomicAdd(&cnt[(epak[i] >> 24) & 255], 1);
  __syncthreads();
  int c = cnt[t];
  scn[t] = c;
  __syncthreads();
  for (int off = 1; off < 256; off <<= 1) {
    int v = (t >= off) ? scn[t - off] : 0;
    __syncthreads();
    scn[t] += v;
    __syncthreads();
  }
  int excl = scn[t] - c;
  int node = b * 256 + t;
  if (node < N) {
    rowptr[node] = ebeg + excl;
    dinv[node] = rsqrtf((float)(c + 1));  // +1 self-loop
  }
  cur[t] = ebeg + excl;
  __syncthreads();
  for (int i = ebeg + t; i < eend; i += 256) {
    int e = epak[i];
    int p = atomicAdd(&cur[(e >> 24) & 255], 1);
    col[p] = e & 0xFFFFFF;
  }
  if (b == 0 && t == 0) rowptr[N] = E;
}

// ---------------- weight fp16 conversion ----------------
__global__ __launch_bounds__(256) void k_prep_w(const float* __restrict__ W1,
                                                const float* __restrict__ W2,
                                                const float* __restrict__ W3,
                                                _Float16* __restrict__ w1h,
                                                _Float16* __restrict__ w2h,
                                                _Float16* __restrict__ w3h) {
  int i = blockIdx.x * 256 + threadIdx.x;
  if (i < 128 * 64) w1h[i] = (_Float16)W1[i];
  if (i < 128 * 128) w2h[i] = (_Float16)W2[i];
  if (i < 64 * 128) w3h[i] = (_Float16)W3[i];
}

// ---------------- prescale: xp = (half)(dinv[row] * x) ----------------
__global__ __launch_bounds__(256) void k_prescaleh(const float* __restrict__ x,
                                                   const float* __restrict__ dinv,
                                                   _Float16* __restrict__ xp, int N) {
  int i = blockIdx.x * 256 + threadIdx.x;  // one float4 per thread
  if (i < N * 16) {
    int row = i >> 4;
    float4 v = ((const float4*)x)[i];
    float d = dinv[row];
    half4 o;
    o[0] = (_Float16)(v.x * d);
    o[1] = (_Float16)(v.y * d);
    o[2] = (_Float16)(v.z * d);
    o[3] = (_Float16)(v.w * d);
    ((half4*)xp)[i] = o;
  }
}

// ---------------- aggregation (pull, 1 row/wave, fp16 tables) ----------------
// input hp pre-scaled by dinv; result = dinv[r] * (sum_nbrs hp[s] + hp[r]).
// EPI 0: write fp16 table. EPI 1: +bias, softmax, write f32 output.

template <int EPI>
__global__ __launch_bounds__(256) void k_agg64h(const _Float16* __restrict__ hp,
                                                const float* __restrict__ dinv,
                                                const int* __restrict__ rowptr,
                                                const int* __restrict__ col,
                                                const float* __restrict__ bias,
                                                void* __restrict__ outp, int N) {
  int wid = blockIdx.x * 4 + (threadIdx.x >> 6);
  int lane = threadIdx.x & 63;
  if (wid >= N) return;
  int g = lane >> 3;
  int fl = (lane & 7) * 8;
  float acc[8] = {0.f, 0.f, 0.f, 0.f, 0.f, 0.f, 0.f, 0.f};
  int r0 = rowptr[wid], r1 = rowptr[wid + 1];
  for (int base = r0; base < r1; base += 64) {
    int mm = min(64, r1 - base);
    int ce = (base + lane < r1) ? col[base + lane] : 0;
    for (int j = 0; j < mm; j += 16) {
      int i0 = j + g, i1 = j + 8 + g;
      int s0 = __shfl(ce, i0);
      int s1 = __shfl(ce, i1);
      if (i0 < mm) {
        half8 v = *(const half8*)&hp[(size_t)s0 * 64 + fl];
#pragma unroll
        for (int k = 0; k < 8; ++k) acc[k] += (float)v[k];
      }
      if (i1 < mm) {
        half8 v = *(const half8*)&hp[(size_t)s1 * 64 + fl];
#pragma unroll
        for (int k = 0; k < 8; ++k) acc[k] += (float)v[k];
      }
    }
  }
#pragma unroll
  for (int o = 8; o < 64; o <<= 1) {
#pragma unroll
    for (int k = 0; k < 8; ++k) acc[k] += __shfl_xor(acc[k], o);
  }
  half8 sv = *(const half8*)&hp[(size_t)wid * 64 + fl];
  float di = dinv[wid];
  float v[8];
#pragma unroll
  for (int k = 0; k < 8; ++k) v[k] = di * (acc[k] + (float)sv[k]);
  if (EPI == 0) {
    if (lane < 8) {
      half8 o;
#pragma unroll
      for (int k = 0; k < 8; ++k) o[k] = (_Float16)v[k];
      *(half8*)&((_Float16*)outp)[(size_t)wid * 64 + fl] = o;
    }
  } else {
    float4 ba = *(const float4*)&bias[fl];
    float4 bb = *(const float4*)&bias[fl + 4];
    v[0] += ba.x; v[1] += ba.y; v[2] += ba.z; v[3] += ba.w;
    v[4] += bb.x; v[5] += bb.y; v[6] += bb.z; v[7] += bb.w;
    float mx = v[0];
#pragma unroll
    for (int k = 1; k < 8; ++k) mx = fmaxf(mx, v[k]);
#pragma unroll
    for (int o = 1; o < 8; o <<= 1) mx = fmaxf(mx, __shfl_xor(mx, o));
    float s = 0.f;
#pragma unroll
    for (int k = 0; k < 8; ++k) {
      v[k] = expf(v[k] - mx);
      s += v[k];
    }
#pragma unroll
    for (int o = 1; o < 8; o <<= 1) s += __shfl_xor(s, o);
    float inv = 1.0f / s;
#pragma unroll
    for (int k = 0; k < 8; ++k) v[k] *= inv;
    if (lane < 8) {
      float4 o0 = make_float4(v[0], v[1], v[2], v[3]);
      float4 o1 = make_float4(v[4], v[5], v[6], v[7]);
      *(float4*)&((float*)outp)[(size_t)wid * 64 + fl] = o0;
      *(float4*)&((float*)outp)[(size_t)wid * 64 + fl + 4] = o1;
    }
  }
}

// F=128: 4 edge-groups x 16 lanes x 8 halves (16B); fp16 output table.
__global__ __launch_bounds__(256) void k_agg128h(const _Float16* __restrict__ hp,
                                                 const float* __restrict__ dinv,
                                                 const int* __restrict__ rowptr,
                                                 const int* __restrict__ col,
                                                 _Float16* __restrict__ out, int N) {
  int wid = blockIdx.x * 4 + (threadIdx.x >> 6);
  int lane = threadIdx.x & 63;
  if (wid >= N) return;
  int g = lane >> 4;
  int fl = (lane & 15) * 8;
  float acc[8] = {0.f, 0.f, 0.f, 0.f, 0.f, 0.f, 0.f, 0.f};
  int r0 = rowptr[wid], r1 = rowptr[wid + 1];
  for (int base = r0; base < r1; base += 64) {
    int mm = min(64, r1 - base);
    int ce = (base + lane < r1) ? col[base + lane] : 0;
    for (int j = 0; j < mm; j += 8) {
      int i0 = j + g, i1 = j + 4 + g;
      int s0 = __shfl(ce, i0);
      int s1 = __shfl(ce, i1);
      if (i0 < mm) {
        half8 v = *(const half8*)&hp[(size_t)s0 * 128 + fl];
#pragma unroll
        for (int k = 0; k < 8; ++k) acc[k] += (float)v[k];
      }
      if (i1 < mm) {
        half8 v = *(const half8*)&hp[(size_t)s1 * 128 + fl];
#pragma unroll
        for (int k = 0; k < 8; ++k) acc[k] += (float)v[k];
      }
    }
  }
#pragma unroll
  for (int o = 16; o < 64; o <<= 1) {
#pragma unroll
    for (int k = 0; k < 8; ++k) acc[k] += __shfl_xor(acc[k], o);
  }
  half8 sv = *(const half8*)&hp[(size_t)wid * 128 + fl];
  float di = dinv[wid];
  if (lane < 16) {
    half8 o;
#pragma unroll
    for (int k = 0; k < 8; ++k) o[k] = (_Float16)(di * (acc[k] + (float)sv[k]));
    *(half8*)&out[(size_t)wid * 128 + fl] = o;
  }
}

// ---------------- MFMA layer kernels ----------------
// Swapped operands: W-frag is the A operand, row-frag is the B operand, so
// D(lane) = row rb+(lane&15), output cols nt*16 + (lane>>4)*4 + reg (4 consecutive).

// h1 = (half) dinv * relu(A1h @ W1^T + b1)   [N,64] -> [N,128]
__global__ __launch_bounds__(256) void k_mfma1(const _Float16* __restrict__ a1h,
                                               const _Float16* __restrict__ w1h,  // [128][64]
                                               const float* __restrict__ b1,
                                               const float* __restrict__ dinv,
                                               _Float16* __restrict__ h1, int N) {
  int wave = threadIdx.x >> 6, lane = threadIdx.x & 63;
  int rb = blockIdx.x * 128 + wave * 32;
  if (rb >= N) return;
  int lrow = lane & 15, lg = lane >> 4;

  half8 arow[2][2];
#pragma unroll
  for (int rt = 0; rt < 2; ++rt) {
    int r = rb + rt * 16 + lrow;
    if (r >= N) r = N - 1;
    const _Float16* p = &a1h[(size_t)r * 64 + lg * 8];
    arow[rt][0] = *(const half8*)p;
    arow[rt][1] = *(const half8*)(p + 32);
  }
  f32x4 acc[2][8];
#pragma unroll
  for (int rt = 0; rt < 2; ++rt)
#pragma unroll
    for (int nt = 0; nt < 8; ++nt) acc[rt][nt] = (f32x4){0.f, 0.f, 0.f, 0.f};

#pragma unroll
  for (int nt = 0; nt < 8; ++nt) {
#pragma unroll
    for (int ks = 0; ks < 2; ++ks) {
      half8 wf = *(const half8*)&w1h[(size_t)(nt * 16 + lrow) * 64 + ks * 32 + lg * 8];
      acc[0][nt] = __builtin_amdgcn_mfma_f32_16x16x32_f16(wf, arow[0][ks], acc[0][nt], 0, 0, 0);
      acc[1][nt] = __builtin_amdgcn_mfma_f32_16x16x32_f16(wf, arow[1][ks], acc[1][nt], 0, 0, 0);
    }
  }
#pragma unroll
  for (int rt = 0; rt < 2; ++rt) {
    int r = rb + rt * 16 + lrow;
    if (r < N) {
      float di = dinv[r];
#pragma unroll
      for (int nt = 0; nt < 8; ++nt) {
        int n = nt * 16 + lg * 4;
        float4 bb = *(const float4*)&b1[n];
        half4 o;
        o[0] = (_Float16)(fmaxf(acc[rt][nt][0] + bb.x, 0.f) * di);
        o[1] = (_Float16)(fmaxf(acc[rt][nt][1] + bb.y, 0.f) * di);
        o[2] = (_Float16)(fmaxf(acc[rt][nt][2] + bb.z, 0.f) * di);
        o[3] = (_Float16)(fmaxf(acc[rt][nt][3] + bb.w, 0.f) * di);
        *(half4*)&h1[(size_t)r * 128 + n] = o;
      }
    }
  }
}

// z = (half) dinv * ( relu(A2h @ W2^T + b2) @ W3^T )   [N,128] -> [N,64]
// u (fp16) staged in per-wave LDS (no barrier needed), re-read as B-frags.
__global__ __launch_bounds__(256) void k_mfma23(const _Float16* __restrict__ a2h,
                                                const _Float16* __restrict__ w2h,  // [128][128]
                                                const float* __restrict__ b2,
                                                const _Float16* __restrict__ w3h,  // [64][128]
                                                const float* __restrict__ dinv,
                                                _Float16* __restrict__ hz, int N) {
  __shared__ _Float16 u_lds[4][32][136];  // pad 128->136 halves: conflict-free frag reads
  int wave = threadIdx.x >> 6, lane = threadIdx.x & 63;
  int rb = blockIdx.x * 128 + wave * 32;
  if (rb >= N) return;
  int lrow = lane & 15, lg = lane >> 4;

  half8 frag[2][4];
#pragma unroll
  for (int rt = 0; rt < 2; ++rt) {
    int r = rb + rt * 16 + lrow;
    if (r >= N) r = N - 1;
    const _Float16* p = &a2h[(size_t)r * 128 + lg * 8];
#pragma unroll
    for (int ks = 0; ks < 4; ++ks) frag[rt][ks] = *(const half8*)(p + ks * 32);
  }
  f32x4 acc[2][8];
#pragma unroll
  for (int rt = 0; rt < 2; ++rt)
#pragma unroll
    for (int nt = 0; nt < 8; ++nt) acc[rt][nt] = (f32x4){0.f, 0.f, 0.f, 0.f};

#pragma unroll
  for (int nt = 0; nt < 8; ++nt) {
#pragma unroll
    for (int ks = 0; ks < 4; ++ks) {
      half8 wf = *(const half8*)&w2h[(size_t)(nt * 16 + lrow) * 128 + ks * 32 + lg * 8];
      acc[0][nt] = __builtin_amdgcn_mfma_f32_16x16x32_f16(wf, frag[0][ks], acc[0][nt], 0, 0, 0);
      acc[1][nt] = __builtin_amdgcn_mfma_f32_16x16x32_f16(wf, frag[1][ks], acc[1][nt], 0, 0, 0);
    }
  }
  // u = relu(acc + b2) -> LDS (fp16)
#pragma unroll
  for (int rt = 0; rt < 2; ++rt) {
#pragma unroll
    for (int nt = 0; nt < 8; ++nt) {
      int n = nt * 16 + lg * 4;
      float4 bb = *(const float4*)&b2[n];
      half4 o;
      o[0] = (_Float16)fmaxf(acc[rt][nt][0] + bb.x, 0.f);
      o[1] = (_Float16)fmaxf(acc[rt][nt][1] + bb.y, 0.f);
      o[2] = (_Float16)fmaxf(acc[rt][nt][2] + bb.z, 0.f);
      o[3] = (_Float16)fmaxf(acc[rt][nt][3] + bb.w, 0.f);
      *(half4*)&u_lds[wave][rt * 16 + lrow][n] = o;
    }
  }
  // re-read u as B-frags (same wave; compiler inserts lgkmcnt)
#pragma unroll
  for (int rt = 0; rt < 2; ++rt)
#pragma unroll
    for (int ks = 0; ks < 4; ++ks)
      frag[rt][ks] = *(const half8*)&u_lds[wave][rt * 16 + lrow][ks * 32 + lg * 8];

  f32x4 acc2[2][4];
#pragma unroll
  for (int rt = 0; rt < 2; ++rt)
#pragma unroll
    for (int mt = 0; mt < 4; ++mt) acc2[rt][mt] = (f32x4){0.f, 0.f, 0.f, 0.f};

#pragma unroll
  for (int mt = 0; mt < 4; ++mt) {
#pragma unroll
    for (int ks = 0; ks < 4; ++ks) {
      half8 wf = *(const half8*)&w3h[(size_t)(mt * 16 + lrow) * 128 + ks * 32 + lg * 8];
      acc2[0][mt] = __builtin_amdgcn_mfma_f32_16x16x32_f16(wf, frag[0][ks], acc2[0][mt], 0, 0, 0);
      acc2[1][mt] = __builtin_amdgcn_mfma_f32_16x16x32_f16(wf, frag[1][ks], acc2[1][mt], 0, 0, 0);
    }
  }
#pragma unroll
  for (int rt = 0; rt < 2; ++rt) {
    int r = rb + rt * 16 + lrow;
    if (r < N) {
      float di = dinv[r];
#pragma unroll
      for (int mt = 0; mt < 4; ++mt) {
        int m = mt * 16 + lg * 4;
        half4 o;
        o[0] = (_Float16)(acc2[rt][mt][0] * di);
        o[1] = (_Float16)(acc2[rt][mt][1] * di);
        o[2] = (_Float16)(acc2[rt][mt][2] * di);
        o[3] = (_Float16)(acc2[rt][mt][3] * di);
        *(half4*)&hz[(size_t)r * 64 + m] = o;
      }
    }
  }
}

// ---------------- launch ----------------

extern "C" void kernel_launch(void* const* d_in, const int* in_sizes, int n_in,
                              void* d_out, int out_size, void* d_ws, size_t ws_size,
                              hipStream_t stream) {
  const float* x  = (const float*)d_in[0];
  const int*   ei = (const int*)d_in[1];
  const float* W1 = (const float*)d_in[2];
  const float* b1 = (const float*)d_in[3];
  const float* W2 = (const float*)d_in[4];
  const float* b2 = (const float*)d_in[5];
  const float* W3 = (const float*)d_in[6];
  const float* b3 = (const float*)d_in[7];
  float* out = (float*)d_out;

  const int N = in_sizes[0] / 64;
  const int E = in_sizes[1] / 2;
  const int* esrc = ei;
  const int* edst = ei + E;

  const int NBUK = (N + 255) / 256;
  const int C1 = (E + NB1 - 1) / NB1;
  const int L = NBUK * NB1;
  const int NA = (L + 255) / 256;

  char* w = (char*)d_ws;
  auto take = [&](size_t bytes) -> void* {
    void* p = (void*)w;
    w += (bytes + 255) & ~(size_t)255;
    return p;
  };
  int*   rowptr = (int*)take((size_t)(N + 1) * 4);
  float* dinv   = (float*)take((size_t)N * 4);
  int*   col    = (int*)take((size_t)E * 4);
  int*   gh     = (int*)take((size_t)L * 4);
  int*   gscan  = (int*)take((size_t)L * 4);
  int*   part   = (int*)take((size_t)NA * 4);
  _Float16* w1h = (_Float16*)take((size_t)128 * 64 * 2);
  _Float16* w2h = (_Float16*)take((size_t)128 * 128 * 2);
  _Float16* w3h = (_Float16*)take((size_t)64 * 128 * 2);
  _Float16* hx  = (_Float16*)take((size_t)N * 64 * 2);   // prescaled x; reused as hz
  _Float16* a1h = (_Float16*)take((size_t)N * 64 * 2);   // agg(x) fp16
  _Float16* h1  = (_Float16*)take((size_t)N * 128 * 2);  // h1p; epak aliases (dead before)
  _Float16* a2h = (_Float16*)take((size_t)N * 128 * 2);  // agg(h1) fp16
  int*   epak   = (int*)h1;   // dead before h1's first write
  _Float16* hz  = hx;         // x-table dead after layer-1 agg

  // CSR build (no global atomics)
  k_hist<<<NB1, 256, 0, stream>>>(edst, E, C1, NBUK, gh);
  k_sum256<<<NA, 256, 0, stream>>>(gh, L, part);
  k_scan_part<<<1, 512, 0, stream>>>(part, NA);
  k_scan_apply<<<NA, 256, 0, stream>>>(gh, L, part, gscan);
  k_scatter<<<NB1, 256, 0, stream>>>(esrc, edst, E, C1, NBUK, gscan, epak);
  k_csr<<<NBUK, 256, 0, stream>>>(epak, gscan, NBUK, N, E, rowptr, dinv, col);

  // weights -> fp16
  k_prep_w<<<64, 256, 0, stream>>>(W1, W2, W3, w1h, w2h, w3h);

  const int aggblocks = (N + 3) / 4;
  const int mfmablocks = (N + 127) / 128;

  // xp = (half) dinv*x
  k_prescaleh<<<(N * 16 + 255) / 256, 256, 0, stream>>>(x, dinv, hx, N);
  // A1h = (half) agg(xp)
  k_agg64h<0><<<aggblocks, 256, 0, stream>>>(hx, dinv, rowptr, col, nullptr, a1h, N);
  // h1 = (half) dinv * relu(A1h @ W1^T + b1)
  k_mfma1<<<mfmablocks, 256, 0, stream>>>(a1h, w1h, b1, dinv, h1, N);
  // A2h = (half) agg(h1)
  k_agg128h<<<aggblocks, 256, 0, stream>>>(h1, dinv, rowptr, col, a2h, N);
  // hz = (half) dinv * (relu(A2h @ W2^T + b2) @ W3^T)
  k_mfma23<<<mfmablocks, 256, 0, stream>>>(a2h, w2h, b2, w3h, dinv, hz, N);
  // out = softmax(agg(hz) + b3)
  k_agg64h<1><<<aggblocks, 256, 0, stream>>>(hz, dinv, rowptr, col, b3, out, N);
}